// Round 9
// baseline (172.200 us; speedup 1.0000x reference)
//
#include <hip/hip_runtime.h>

// ---------------------------------------------------------------------------
// SelfAttention: B=4, N=4096 tokens/batch, C=512, DQK=64
// out = gamma * softmax((X Wf)(X Wg)^T) (X Wh) + X
// Round 9: fat-wave attention — 64 q-rows/wave (halves per-CU LDS traffic,
// the measured bottleneck), 1 block/CU, ~300 VGPR at 1 wave/SIMD,
// XCD-aware batch mapping. proj_k/cvt_w unchanged from R8.
// ---------------------------------------------------------------------------

typedef __bf16 bf16x8 __attribute__((ext_vector_type(8)));
typedef __bf16 bf16x2 __attribute__((ext_vector_type(2)));
typedef float f32x4 __attribute__((ext_vector_type(4)));
typedef unsigned int u32x4 __attribute__((ext_vector_type(4)));
typedef unsigned int u32;

#define L2E 1.4426950408889634f

__device__ __forceinline__ unsigned short f2bf(float f) {
    unsigned int u = __builtin_bit_cast(unsigned int, f);
    u += 0x7fffu + ((u >> 16) & 1u);   // RNE
    return (unsigned short)(u >> 16);
}
__device__ __forceinline__ u32 cvtpk(float a, float b) {
    bf16x2 t; t[0] = (__bf16)a; t[1] = (__bf16)b;   // -> v_cvt_pk_bf16_f32
    return __builtin_bit_cast(u32, t);
}
__device__ __forceinline__ bf16x8 ld8(const void* p) {
    u32x4 u = *reinterpret_cast<const u32x4*>(p);
    return __builtin_bit_cast(bf16x8, u);
}
// two float4 loads + cvt_pk -> bf16x8 fragment
__device__ __forceinline__ bf16x8 ldx(const float* p) {
    float4 a = *reinterpret_cast<const float4*>(p);
    float4 b = *reinterpret_cast<const float4*>(p + 4);
    u32x4 r;
    r.x = cvtpk(a.x, a.y); r.y = cvtpk(a.z, a.w);
    r.z = cvtpk(b.x, b.y); r.w = cvtpk(b.z, b.w);
    return __builtin_bit_cast(bf16x8, r);
}
__device__ __forceinline__ f32x4 mfma16(bf16x8 a, bf16x8 b, f32x4 c) {
    return __builtin_amdgcn_mfma_f32_16x16x32_bf16(a, b, c, 0, 0, 0);
}
__device__ __forceinline__ void gl2lds16(const void* g, void* l) {
    __builtin_amdgcn_global_load_lds(
        (const __attribute__((address_space(1))) u32*)g,
        (__attribute__((address_space(3))) u32*)l, 16, 0, 0);
}

// --------------------------- prep kernel -----------------------------------
// W -> staged layout [16 chunks q][4 slots s][640 cols c][8 bf16]:
//   element (q,s,c,j) = W^T[c][k=32q+8s+j];  c<64: f (x log2e), c<128: g,
//   c>=128: h col c-128.
__global__ __launch_bounds__(256) void cvt_w_all(const float* __restrict__ kf,
                                                 const float* __restrict__ kg,
                                                 const float* __restrict__ kh,
                                                 unsigned short* __restrict__ wst) {
    int idx = blockIdx.x * 256 + threadIdx.x;   // 327680 total
    int j = idx & 7;
    int gi = idx >> 3;
    int c = gi % 640;
    int sq = gi / 640;
    int k = (sq >> 2) * 32 + (sq & 3) * 8 + j;
    float v;
    if (c < 64)       v = kf[k * 64 + c] * L2E;
    else if (c < 128) v = kg[k * 64 + (c - 64)];
    else              v = kh[k * 512 + (c - 128)];
    wst[idx] = f2bf(v);
}

// --------------------- fused projection kernel -----------------------------
// Grid dim3(256, 2); W streamed through 2x20KB LDS dbuf via global_load_lds.
__global__ __launch_bounds__(256, 2) void proj_k(const float* __restrict__ x,
                                                 const unsigned short* __restrict__ wst,
                                                 unsigned short* __restrict__ fgb,
                                                 unsigned short* __restrict__ vt) {
    __shared__ __align__(16) unsigned char Wl[2][20480];   // [4 slots][320 cols][16B]
    __shared__ unsigned short Tl[64][72];

    int m0 = blockIdx.x * 64;
    int grp = blockIdx.y;
    int tid = threadIdx.x;
    int w = tid >> 6, l = tid & 63, g = l >> 4, i = l & 15;

    const char* wsrc = (const char*)wst + (size_t)w * 10240 + (size_t)grp * 5120 + l * 16;

#pragma unroll
    for (int s5 = 0; s5 < 5; s5++)
        gl2lds16(wsrc + s5 * 1024, &Wl[0][w * 5120 + s5 * 1024]);

    const float* xrow = x + (size_t)(m0 + 16 * w + i) * 512 + g * 8;
    bf16x8 af[16];
#pragma unroll
    for (int k = 0; k < 16; k++) af[k] = ldx(xrow + 32 * k);

    f32x4 acc[5][4];
#pragma unroll
    for (int t = 0; t < 5; t++)
#pragma unroll
        for (int cf = 0; cf < 4; cf++) acc[t][cf] = f32x4{0, 0, 0, 0};

    int rdoff = g * 5120 + i * 16;

#pragma unroll
    for (int q = 0; q < 16; q++) {
        __syncthreads();

        if (q < 15) {
            const char* src = wsrc + (size_t)(q + 1) * 40960;
#pragma unroll
            for (int s5 = 0; s5 < 5; s5++)
                gl2lds16(src + s5 * 1024, &Wl[(q + 1) & 1][w * 5120 + s5 * 1024]);
        }

        const unsigned char* Wb = &Wl[q & 1][0];
        __builtin_amdgcn_s_setprio(1);
#pragma unroll
        for (int t = 0; t < 5; t++)
#pragma unroll
            for (int cf = 0; cf < 4; cf++) {
                bf16x8 bb = ld8(Wb + rdoff + (t * 64 + 16 * cf) * 16);
                acc[t][cf] = mfma16(af[q], bb, acc[t][cf]);
            }
        __builtin_amdgcn_s_setprio(0);
    }

    int b = m0 >> 12, n = m0 & 4095;

#pragma unroll
    for (int t = 0; t < 5; t++) {
        bool isfg = (grp == 0) && (t < 2);
        if (isfg) {
#pragma unroll
            for (int cf = 0; cf < 4; cf++)
#pragma unroll
                for (int r = 0; r < 4; r++)
                    fgb[(size_t)(m0 + 16 * w + 4 * g + r) * 128 + t * 64 + 16 * cf + i] =
                        f2bf(acc[t][cf][r]);
        } else {
            int n0 = (grp == 0) ? (t - 2) * 64 : 192 + t * 64;
            __syncthreads();
#pragma unroll
            for (int cf = 0; cf < 4; cf++) {
                ushort4 v4;
                v4.x = f2bf(acc[t][cf][0]); v4.y = f2bf(acc[t][cf][1]);
                v4.z = f2bf(acc[t][cf][2]); v4.w = f2bf(acc[t][cf][3]);
                *reinterpret_cast<ushort4*>(&Tl[16 * cf + i][16 * w + 4 * g]) = v4;
            }
            __syncthreads();
#pragma unroll
            for (int ch = tid; ch < 1024; ch += 256) {
                int row = ch >> 4, nq = ch & 15;
                int w32 = nq >> 3, wq = nq & 7;
                int pos = w32 * 32 + (((wq & 3) << 1) + (wq >> 2)) * 4;
                ushort4 d = *reinterpret_cast<const ushort4*>(&Tl[row][nq * 4]);
                *reinterpret_cast<ushort4*>(vt + ((size_t)(b * 512 + n0 + row)) * 4096 + n + pos) = d;
            }
        }
    }
}

// --------------------------- flash attention -------------------------------
// Grid 256 = 1 block/CU; block = 4 waves x 64 q-rows = 256-row q-tile,
// c-slice 128. Halves per-CU LDS traffic vs 32-row waves (the bottleneck).
// K/V double-buffered via global_load_lds; P in registers (sigma k-order);
// l via ones-MFMA. XCD mapping: 2 XCDs per batch (KV L2-resident).
__global__ __launch_bounds__(256, 1) void attn_k(const unsigned short* __restrict__ fg,
                                                 const unsigned short* __restrict__ vt,
                                                 const float* __restrict__ x,
                                                 const float* __restrict__ gamma,
                                                 float* __restrict__ out) {
    __shared__ __align__(16) unsigned char Kl[2][8192];    // [64 j][128 B], XOR-swz
    __shared__ __align__(16) unsigned char Vl[2][16384];   // [128 c][128 B], XOR-swz

    int bid = blockIdx.x;
    int xcd = bid & 7;
    int batch = xcd >> 1;                  // 2 XCDs per batch
    int r = bid >> 3;                      // 0..31
    int cs = ((xcd & 1) << 1) | (r & 1);   // 0..3
    int q = r >> 1;                        // 0..15
    int c0w = cs * 128;

    int tid = threadIdx.x;
    int w = tid >> 6, l = tid & 63, g = l >> 4, i = l & 15;
    int swz = (i & 7) << 4;
    int qbase = q * 256 + 64 * w;

    const unsigned short* fgb = fg + (size_t)batch * 4096 * 128;
    const char* vtB = (const char*)(vt + (size_t)batch * 512 * 4096);

    // staging source addresses (inverse-swizzled; LDS dest linear per lane)
    int kcol = (16 * (l & 7)) ^ (16 * (l >> 3));
    const char* kbase = (const char*)fgb + 128 + kcol + (size_t)(16 * w + (l >> 3)) * 256;
    const char* vbase = vtB + (size_t)(c0w + 32 * w + (l >> 3)) * 8192 + kcol;

    int koff0 = (16 * g) ^ swz, koff1 = (64 + 16 * g) ^ swz;

    // Q fragments: 4 q-frags x 2 k-slots, register-resident
    bf16x8 aQ[4][2];
#pragma unroll
    for (int qf = 0; qf < 4; qf++)
#pragma unroll
        for (int ks = 0; ks < 2; ks++)
            aQ[qf][ks] = ld8(fgb + (size_t)(qbase + 16 * qf + i) * 128 + ks * 32 + g * 8);

    bf16x8 ones8;
#pragma unroll
    for (int z = 0; z < 8; z++) ones8[z] = (__bf16)1.0f;

    f32x4 acc[4][8];
#pragma unroll
    for (int a = 0; a < 4; a++)
#pragma unroll
        for (int b = 0; b < 8; b++) acc[a][b] = f32x4{0, 0, 0, 0};
    f32x4 lacc[4] = {f32x4{0,0,0,0}, f32x4{0,0,0,0}, f32x4{0,0,0,0}, f32x4{0,0,0,0}};

    // prologue: stage tile 0 into buf 0
    {
        unsigned char* Kd = &Kl[0][w * 2048];
        gl2lds16(kbase, Kd);
        gl2lds16(kbase + 2048, Kd + 1024);
        unsigned char* Vd = &Vl[0][w * 4096];
        gl2lds16(vbase, Vd);
        gl2lds16(vbase + 65536, Vd + 1024);
        gl2lds16(vbase + 131072, Vd + 2048);
        gl2lds16(vbase + 196608, Vd + 3072);
    }

    int p = 0;
    for (int t = 0; t < 64; ++t) {
        __syncthreads();   // vmcnt(0): stage(t) landed; all waves done with buf p^1

        if (t + 1 < 64) {  // stage tile t+1 into buf p^1
            size_t j0n = (size_t)(t + 1) * 64;
            unsigned char* Kd = &Kl[p ^ 1][w * 2048];
            const char* gk = kbase + j0n * 256;
            gl2lds16(gk, Kd);
            gl2lds16(gk + 2048, Kd + 1024);
            unsigned char* Vd = &Vl[p ^ 1][w * 4096];
            const char* gv = vbase + j0n * 2;
            gl2lds16(gv, Vd);
            gl2lds16(gv + 65536, Vd + 1024);
            gl2lds16(gv + 131072, Vd + 2048);
            gl2lds16(gv + 196608, Vd + 3072);
        }

        // ---- K tile -> registers (read once, reused by all 4 q-frags) ----
        const unsigned char* Kb = Kl[p];
        bf16x8 kreg[4][2];
#pragma unroll
        for (int jf = 0; jf < 4; jf++) {
            const unsigned char* ra = Kb + (16 * jf + i) * 128;
            kreg[jf][0] = ld8(ra + koff0);
            kreg[jf][1] = ld8(ra + koff1);
        }

        // ---- S^T(log2) = K Q^T : lane holds S[q=16qf+i][j=16jf+4g+r] ----
        f32x4 sacc[4][4];
#pragma unroll
        for (int jf = 0; jf < 4; jf++)
#pragma unroll
            for (int qf = 0; qf < 4; qf++) sacc[jf][qf] = f32x4{0, 0, 0, 0};
        __builtin_amdgcn_s_setprio(1);
#pragma unroll
        for (int jf = 0; jf < 4; jf++)
#pragma unroll
            for (int qf = 0; qf < 4; qf++) {
                sacc[jf][qf] = mfma16(kreg[jf][0], aQ[qf][0], sacc[jf][qf]);
                sacc[jf][qf] = mfma16(kreg[jf][1], aQ[qf][1], sacc[jf][qf]);
            }
        __builtin_amdgcn_s_setprio(0);

        // ---- P = exp2(S) (bounded; no max pass), pack to A-frags in regs ----
        bf16x8 aP[4][2];
#pragma unroll
        for (int qf = 0; qf < 4; qf++) {
            u32 pk[4][2];
#pragma unroll
            for (int jf = 0; jf < 4; jf++) {
                float p0 = __builtin_amdgcn_exp2f(sacc[jf][qf][0]);
                float p1 = __builtin_amdgcn_exp2f(sacc[jf][qf][1]);
                float p2 = __builtin_amdgcn_exp2f(sacc[jf][qf][2]);
                float p3 = __builtin_amdgcn_exp2f(sacc[jf][qf][3]);
                pk[jf][0] = cvtpk(p0, p1);
                pk[jf][1] = cvtpk(p2, p3);
            }
            aP[qf][0] = __builtin_bit_cast(bf16x8, u32x4{pk[0][0], pk[0][1], pk[1][0], pk[1][1]});
            aP[qf][1] = __builtin_bit_cast(bf16x8, u32x4{pk[2][0], pk[2][1], pk[3][0], pk[3][1]});
        }

        // ---- O += P @ V ; l += P @ 1 ----
        const unsigned char* Vb = Vl[p];
        __builtin_amdgcn_s_setprio(1);
#pragma unroll
        for (int cf = 0; cf < 8; cf++) {
            const unsigned char* rv = Vb + (16 * cf + i) * 128;
            bf16x8 v0 = ld8(rv + koff0);
            bf16x8 v1 = ld8(rv + koff1);
#pragma unroll
            for (int qf = 0; qf < 4; qf++) {
                acc[qf][cf] = mfma16(aP[qf][0], v0, acc[qf][cf]);
                acc[qf][cf] = mfma16(aP[qf][1], v1, acc[qf][cf]);
            }
        }
#pragma unroll
        for (int qf = 0; qf < 4; qf++) {
            lacc[qf] = mfma16(aP[qf][0], ones8, lacc[qf]);
            lacc[qf] = mfma16(aP[qf][1], ones8, lacc[qf]);
        }
        __builtin_amdgcn_s_setprio(0);
        p ^= 1;
    }

    // ---- epilogue: out = gamma*O/l + x (l per-lane in lacc) ----
    float gam = gamma[0];
#pragma unroll
    for (int qf = 0; qf < 4; qf++) {
#pragma unroll
        for (int r2 = 0; r2 < 4; r2++) {
            float linv = gam / lacc[qf][r2];
            int n = qbase + 16 * qf + 4 * g + r2;
            size_t base = ((size_t)batch * 4096 + n) * 512 + c0w;
#pragma unroll
            for (int cf = 0; cf < 8; cf++)
                out[base + 16 * cf + i] = acc[qf][cf][r2] * linv + x[base + 16 * cf + i];
        }
    }
}

// --------------------------- launcher --------------------------------------

extern "C" void kernel_launch(void* const* d_in, const int* in_sizes, int n_in,
                              void* d_out, int out_size, void* d_ws, size_t ws_size,
                              hipStream_t stream) {
    const float* x = (const float*)d_in[0];
    const float* kf = (const float*)d_in[1];
    const float* kg = (const float*)d_in[2];
    const float* kh = (const float*)d_in[3];
    const float* gamma = (const float*)d_in[4];
    float* out = (float*)d_out;

    char* ws = (char*)d_ws;
    unsigned short* FGb = (unsigned short*)(ws);               // 4 MB
    unsigned short* Vt  = (unsigned short*)(ws + 4194304);     // 16 MB
    unsigned short* Wst = (unsigned short*)(ws + 20971520);    // 640 KB

    cvt_w_all<<<1280, 256, 0, stream>>>(kf, kg, kh, Wst);
    proj_k<<<dim3(256, 2), 256, 0, stream>>>(x, Wst, FGb, Vt);
    attn_k<<<256, 256, 0, stream>>>(FGb, Vt, x, gamma, out);
}

// Round 10
// 120.250 us; speedup vs baseline: 1.4320x; 1.4320x over previous
//
#include <hip/hip_runtime.h>

// ---------------------------------------------------------------------------
// SelfAttention: B=4, N=4096 tokens/batch, C=512, DQK=64
// out = gamma * softmax((X Wf)(X Wg)^T) (X Wh) + X
// Round 10: shared-P attention — P computed ONCE per (q,KV-tile) (kills the
// 4x c-slice replication of QK^T+exp2), shared via fragment-major LDS dbuf;
// V and K read direct global->reg from fragment-stream layouts emitted by
// proj_k (coalesced 1KB chunks, L2-resident per XCD). 8 waves, 2/SIMD.
// ---------------------------------------------------------------------------

typedef __bf16 bf16x8 __attribute__((ext_vector_type(8)));
typedef __bf16 bf16x2 __attribute__((ext_vector_type(2)));
typedef float f32x4 __attribute__((ext_vector_type(4)));
typedef unsigned int u32x4 __attribute__((ext_vector_type(4)));
typedef unsigned int u32;

#define L2E 1.4426950408889634f

__device__ __forceinline__ unsigned short f2bf(float f) {
    unsigned int u = __builtin_bit_cast(unsigned int, f);
    u += 0x7fffu + ((u >> 16) & 1u);   // RNE
    return (unsigned short)(u >> 16);
}
__device__ __forceinline__ u32 cvtpk(float a, float b) {
    bf16x2 t; t[0] = (__bf16)a; t[1] = (__bf16)b;   // -> v_cvt_pk_bf16_f32
    return __builtin_bit_cast(u32, t);
}
__device__ __forceinline__ bf16x8 ld8(const void* p) {
    u32x4 u = *reinterpret_cast<const u32x4*>(p);
    return __builtin_bit_cast(bf16x8, u);
}
__device__ __forceinline__ bf16x8 ldx(const float* p) {
    float4 a = *reinterpret_cast<const float4*>(p);
    float4 b = *reinterpret_cast<const float4*>(p + 4);
    u32x4 r;
    r.x = cvtpk(a.x, a.y); r.y = cvtpk(a.z, a.w);
    r.z = cvtpk(b.x, b.y); r.w = cvtpk(b.z, b.w);
    return __builtin_bit_cast(bf16x8, r);
}
__device__ __forceinline__ f32x4 mfma16(bf16x8 a, bf16x8 b, f32x4 c) {
    return __builtin_amdgcn_mfma_f32_16x16x32_bf16(a, b, c, 0, 0, 0);
}
__device__ __forceinline__ void gl2lds16(const void* g, void* l) {
    __builtin_amdgcn_global_load_lds(
        (const __attribute__((address_space(1))) u32*)g,
        (__attribute__((address_space(3))) u32*)l, 16, 0, 0);
}

// --------------------------- prep kernel -----------------------------------
// W -> staged layout [16 chunks q][4 slots s][640 cols c][8 bf16]:
//   (q,s,c,j) = W^T[c][k=32q+8s+j]; c<64: f (x log2e), c<128: g, else h.
__global__ __launch_bounds__(256) void cvt_w_all(const float* __restrict__ kf,
                                                 const float* __restrict__ kg,
                                                 const float* __restrict__ kh,
                                                 unsigned short* __restrict__ wst) {
    int idx = blockIdx.x * 256 + threadIdx.x;   // 327680 total
    int j = idx & 7;
    int gi = idx >> 3;
    int c = gi % 640;
    int sq = gi / 640;
    int k = (sq >> 2) * 32 + (sq & 3) * 8 + j;
    float v;
    if (c < 64)       v = kf[k * 64 + c] * L2E;
    else if (c < 128) v = kg[k * 64 + (c - 64)];
    else              v = kh[k * 512 + (c - 128)];
    wst[idx] = f2bf(v);
}

// --------------------- fused projection kernel -----------------------------
// Grid dim3(256, 2). W streamed via 2x20KB LDS dbuf (global_load_lds).
// Outputs:
//   fq  [16384][64]  : f rows (Q), row-major bf16
//   kst [4][64t][4jf][2ks][64l][16B] : K A-fragment stream
//   vst [4][64t][32c16][2ks][64l][16B] : V B-fragment stream (sigma j-order)
__global__ __launch_bounds__(256, 2) void proj_k(const float* __restrict__ x,
                                                 const unsigned short* __restrict__ wst,
                                                 unsigned short* __restrict__ fq,
                                                 unsigned short* __restrict__ kst,
                                                 unsigned short* __restrict__ vst) {
    __shared__ __align__(16) unsigned char Wl[2][20480];
    __shared__ unsigned short Tl[64][72];

    int m0 = blockIdx.x * 64;
    int grp = blockIdx.y;
    int tid = threadIdx.x;
    int w = tid >> 6, l = tid & 63, g = l >> 4, i = l & 15;

    const char* wsrc = (const char*)wst + (size_t)w * 10240 + (size_t)grp * 5120 + l * 16;

#pragma unroll
    for (int s5 = 0; s5 < 5; s5++)
        gl2lds16(wsrc + s5 * 1024, &Wl[0][w * 5120 + s5 * 1024]);

    const float* xrow = x + (size_t)(m0 + 16 * w + i) * 512 + g * 8;
    bf16x8 af[16];
#pragma unroll
    for (int k = 0; k < 16; k++) af[k] = ldx(xrow + 32 * k);

    f32x4 acc[5][4];
#pragma unroll
    for (int t = 0; t < 5; t++)
#pragma unroll
        for (int cf = 0; cf < 4; cf++) acc[t][cf] = f32x4{0, 0, 0, 0};

    int rdoff = g * 5120 + i * 16;

#pragma unroll
    for (int q = 0; q < 16; q++) {
        __syncthreads();
        if (q < 15) {
            const char* src = wsrc + (size_t)(q + 1) * 40960;
#pragma unroll
            for (int s5 = 0; s5 < 5; s5++)
                gl2lds16(src + s5 * 1024, &Wl[(q + 1) & 1][w * 5120 + s5 * 1024]);
        }
        const unsigned char* Wb = &Wl[q & 1][0];
        __builtin_amdgcn_s_setprio(1);
#pragma unroll
        for (int t = 0; t < 5; t++)
#pragma unroll
            for (int cf = 0; cf < 4; cf++) {
                bf16x8 bb = ld8(Wb + rdoff + (t * 64 + 16 * cf) * 16);
                acc[t][cf] = mfma16(af[q], bb, acc[t][cf]);
            }
        __builtin_amdgcn_s_setprio(0);
    }

    int batch = m0 >> 12;
    int kt = (m0 & 4095) >> 6;   // KV tile index (this block's 64 tokens)
    unsigned short* kbase = kst + (size_t)batch * 262144 + (size_t)kt * 4096;
    unsigned short* vbase = vst + (size_t)batch * 2097152 + (size_t)kt * 32768;

#pragma unroll
    for (int t = 0; t < 5; t++) {
        if (grp == 0 && t == 0) {
            // f tile -> row-major Q buffer
#pragma unroll
            for (int cf = 0; cf < 4; cf++)
#pragma unroll
                for (int r = 0; r < 4; r++)
                    fq[(size_t)(m0 + 16 * w + 4 * g + r) * 64 + 16 * cf + i] =
                        f2bf(acc[t][cf][r]);
        } else {
            __syncthreads();   // prior emission reads done
            // Tl[out-channel][token]
#pragma unroll
            for (int cf = 0; cf < 4; cf++) {
                ushort4 v4;
                v4.x = f2bf(acc[t][cf][0]); v4.y = f2bf(acc[t][cf][1]);
                v4.z = f2bf(acc[t][cf][2]); v4.w = f2bf(acc[t][cf][3]);
                *reinterpret_cast<ushort4*>(&Tl[16 * cf + i][16 * w + 4 * g]) = v4;
            }
            __syncthreads();
            if (grp == 0 && t == 1) {
                // g tile -> K fragment stream: chunk (jf,ks), lane(g2,i2):
                // K[j=16jf+i2][d=ks*32+8g2+jj]
#pragma unroll
                for (int ch = tid; ch < 512; ch += 256) {
                    int jf2 = ch >> 7, ks = (ch >> 6) & 1, l2 = ch & 63;
                    int g2 = l2 >> 4, i2 = l2 & 15;
                    ushort4 o0, o1;
                    o0.x = Tl[ks * 32 + 8 * g2 + 0][16 * jf2 + i2];
                    o0.y = Tl[ks * 32 + 8 * g2 + 1][16 * jf2 + i2];
                    o0.z = Tl[ks * 32 + 8 * g2 + 2][16 * jf2 + i2];
                    o0.w = Tl[ks * 32 + 8 * g2 + 3][16 * jf2 + i2];
                    o1.x = Tl[ks * 32 + 8 * g2 + 4][16 * jf2 + i2];
                    o1.y = Tl[ks * 32 + 8 * g2 + 5][16 * jf2 + i2];
                    o1.z = Tl[ks * 32 + 8 * g2 + 6][16 * jf2 + i2];
                    o1.w = Tl[ks * 32 + 8 * g2 + 7][16 * jf2 + i2];
                    unsigned short* dst = kbase + (size_t)(jf2 * 1024 + ks * 512 + l2 * 8);
                    *reinterpret_cast<ushort4*>(dst)     = o0;
                    *reinterpret_cast<ushort4*>(dst + 4) = o1;
                }
            } else {
                // V tile -> B fragment stream (sigma j-order):
                // elem jj of lane(g2,i2),ks: V[j=16*(2ks+(jj>>2))+4g2+(jj&3)][c]
                int n0 = (grp == 0) ? (t - 2) * 64 : 192 + t * 64;
#pragma unroll
                for (int ch = tid; ch < 512; ch += 256) {
                    int cc = ch >> 7, ks = (ch >> 6) & 1, l2 = ch & 63;
                    int g2 = l2 >> 4, i2 = l2 & 15;
                    int row = cc * 16 + i2;
                    int jb = 32 * ks + 4 * g2;
                    ushort4 o0, o1;
                    o0.x = Tl[row][jb + 0];  o0.y = Tl[row][jb + 1];
                    o0.z = Tl[row][jb + 2];  o0.w = Tl[row][jb + 3];
                    o1.x = Tl[row][jb + 16]; o1.y = Tl[row][jb + 17];
                    o1.z = Tl[row][jb + 18]; o1.w = Tl[row][jb + 19];
                    int c16 = (n0 >> 4) + cc;
                    unsigned short* dst = vbase + (size_t)(c16 * 1024 + ks * 512 + l2 * 8);
                    *reinterpret_cast<ushort4*>(dst)     = o0;
                    *reinterpret_cast<ushort4*>(dst + 4) = o1;
                }
            }
        }
    }
}

// --------------------------- shared-P attention ----------------------------
// Grid 256 = 4 batch x 64 q-tiles(64 rows); block 512 thr / 8 waves.
// Per tile: each wave computes 1/8 of S^T (4 MFMA) + exp2 + packs to LDS P
// (fragment-major, double-buffered); ONE barrier; each wave PVs its 64-col
// slice with P from LDS and V direct from the fragment stream. l via VALU
// partials + epilogue LDS atomic reduce.
__global__ __launch_bounds__(512, 2) void attn_k(const unsigned short* __restrict__ fq,
                                                 const unsigned short* __restrict__ kst,
                                                 const unsigned short* __restrict__ vst,
                                                 const float* __restrict__ x,
                                                 const float* __restrict__ gamma,
                                                 float* __restrict__ out) {
    __shared__ __align__(16) unsigned char Pl[2][8192];   // [buf][qf][ks][64l][16B]
    __shared__ float l_lds[64];

    int bid = blockIdx.x;
    int xcd = bid & 7;
    int batch = xcd >> 1;                       // 2 XCDs per batch
    int qidx = ((xcd & 1) << 5) | (bid >> 3);   // 0..63
    int q0 = qidx * 64;

    int tid = threadIdx.x;
    int w = tid >> 6, l = tid & 63, g = l >> 4, i = l & 15;
    int jf = w >> 1, qfh = w & 1;               // S-duty: (jf, qf in {2qfh,2qfh+1})

    if (tid < 64) l_lds[tid] = 0.0f;

    const unsigned short* fqb = fq + (size_t)batch * 4096 * 64;
    const char* kb = (const char*)kst + (size_t)batch * 524288;
    const char* vb = (const char*)vst + (size_t)batch * 4194304;

    // Q fragments for this wave's two q-frags
    bf16x8 aQ[2][2];
#pragma unroll
    for (int qf_l = 0; qf_l < 2; qf_l++)
#pragma unroll
        for (int ks = 0; ks < 2; ks++)
            aQ[qf_l][ks] = ld8(fqb + (size_t)(q0 + 16 * (2 * qfh + qf_l) + i) * 64 +
                               ks * 32 + g * 8);

    f32x4 acc[4][4];
#pragma unroll
    for (int a = 0; a < 4; a++)
#pragma unroll
        for (int b = 0; b < 4; b++) acc[a][b] = f32x4{0, 0, 0, 0};
    float lp[2] = {0.0f, 0.0f};

    // K fragments for tile 0
    bf16x8 kA[2];
#pragma unroll
    for (int ks = 0; ks < 2; ks++)
        kA[ks] = ld8(kb + (size_t)jf * 2048 + ks * 1024 + l * 16);

    int pwoff = ((2 * qfh) * 2 + (jf >> 1)) * 1024 + l * 16 + (jf & 1) * 8;

    for (int t = 0; t < 64; ++t) {
        // V loads for this tile (coalesced 1KB chunks; used after the barrier)
        bf16x8 vB[4][2];
#pragma unroll
        for (int cf = 0; cf < 4; cf++)
#pragma unroll
            for (int ks = 0; ks < 2; ks++)
                vB[cf][ks] = ld8(vb + (size_t)(t * 32 + w * 4 + cf) * 2048 +
                                 ks * 1024 + l * 16);

        // ---- S slice: lane holds S[q=16qf+i][j=16jf+4g+r] (log2 domain) ----
        f32x4 sacc[2] = {f32x4{0,0,0,0}, f32x4{0,0,0,0}};
#pragma unroll
        for (int qf_l = 0; qf_l < 2; qf_l++) {
            sacc[qf_l] = mfma16(kA[0], aQ[qf_l][0], sacc[qf_l]);
            sacc[qf_l] = mfma16(kA[1], aQ[qf_l][1], sacc[qf_l]);
        }

        // K prefetch for next tile (wraps at 63 -> dummy reload of tile 0)
        {
            int tn = (t + 1) & 63;
            const char* kn = kb + (size_t)(tn * 4 + jf) * 2048;
            kA[0] = ld8(kn + l * 16);
            kA[1] = ld8(kn + 1024 + l * 16);
        }

        // ---- P slice = exp2(S), pack bf16, write 2x8B to LDS ----
        unsigned char* Pb = &Pl[t & 1][0];
#pragma unroll
        for (int qf_l = 0; qf_l < 2; qf_l++) {
            float p0 = __builtin_amdgcn_exp2f(sacc[qf_l][0]);
            float p1 = __builtin_amdgcn_exp2f(sacc[qf_l][1]);
            float p2 = __builtin_amdgcn_exp2f(sacc[qf_l][2]);
            float p3 = __builtin_amdgcn_exp2f(sacc[qf_l][3]);
            lp[qf_l] += (p0 + p1) + (p2 + p3);
            uint2 pk2;
            pk2.x = cvtpk(p0, p1);
            pk2.y = cvtpk(p2, p3);
            *reinterpret_cast<uint2*>(Pb + pwoff + qf_l * 2048) = pk2;
        }

        __syncthreads();   // P(t) complete; also orders P-buf reuse (dbuf)

        // ---- PV: all four q-frags x this wave's 4 c-frags ----
        const unsigned char* Pr = &Pl[t & 1][0];
        bf16x8 aP[4][2];
#pragma unroll
        for (int qf = 0; qf < 4; qf++)
#pragma unroll
            for (int ks = 0; ks < 2; ks++)
                aP[qf][ks] = ld8(Pr + (qf * 2 + ks) * 1024 + l * 16);

        __builtin_amdgcn_s_setprio(1);
#pragma unroll
        for (int cf = 0; cf < 4; cf++)
#pragma unroll
            for (int qf = 0; qf < 4; qf++) {
                acc[qf][cf] = mfma16(aP[qf][0], vB[cf][0], acc[qf][cf]);
                acc[qf][cf] = mfma16(aP[qf][1], vB[cf][1], acc[qf][cf]);
            }
        __builtin_amdgcn_s_setprio(0);
    }

    // ---- l reduction: in-wave over g, cross-wave (4 jf) via LDS atomics ----
#pragma unroll
    for (int qf_l = 0; qf_l < 2; qf_l++) {
        lp[qf_l] += __shfl_xor(lp[qf_l], 16, 64);
        lp[qf_l] += __shfl_xor(lp[qf_l], 32, 64);
    }
    if (g == 0) {
        atomicAdd(&l_lds[16 * (2 * qfh + 0) + i], lp[0]);
        atomicAdd(&l_lds[16 * (2 * qfh + 1) + i], lp[1]);
    }
    __syncthreads();

    // ---- epilogue: out = gamma*O/l + x ----
    float gam = gamma[0];
#pragma unroll
    for (int qf = 0; qf < 4; qf++) {
#pragma unroll
        for (int r = 0; r < 4; r++) {
            float linv = gam / l_lds[16 * qf + 4 * g + r];
            int n = q0 + 16 * qf + 4 * g + r;
            size_t base = ((size_t)batch * 4096 + n) * 512 + 64 * w;
#pragma unroll
            for (int cf = 0; cf < 4; cf++)
                out[base + 16 * cf + i] = acc[qf][cf][r] * linv + x[base + 16 * cf + i];
        }
    }
}

// --------------------------- launcher --------------------------------------

extern "C" void kernel_launch(void* const* d_in, const int* in_sizes, int n_in,
                              void* d_out, int out_size, void* d_ws, size_t ws_size,
                              hipStream_t stream) {
    const float* x = (const float*)d_in[0];
    const float* kf = (const float*)d_in[1];
    const float* kg = (const float*)d_in[2];
    const float* kh = (const float*)d_in[3];
    const float* gamma = (const float*)d_in[4];
    float* out = (float*)d_out;

    char* ws = (char*)d_ws;
    unsigned short* Fq  = (unsigned short*)(ws);               // 2 MB
    unsigned short* Kst = (unsigned short*)(ws + 2097152);     // 2 MB
    unsigned short* Vst = (unsigned short*)(ws + 4194304);     // 16 MB
    unsigned short* Wst = (unsigned short*)(ws + 20971520);    // 640 KB

    cvt_w_all<<<1280, 256, 0, stream>>>(kf, kg, kh, Wst);
    proj_k<<<dim3(256, 2), 256, 0, stream>>>(x, Wst, Fq, Kst, Vst);
    attn_k<<<256, 512, 0, stream>>>(Fq, Kst, Vst, x, gamma, out);
}

// Round 11
// 116.835 us; speedup vs baseline: 1.4739x; 1.0292x over previous
//
#include <hip/hip_runtime.h>

// ---------------------------------------------------------------------------
// SelfAttention: B=4, N=4096 tokens/batch, C=512, DQK=64
// out = gamma * softmax((X Wf)(X Wg)^T) (X Wh) + X
// Round 11: software-pipelined shared-P attention — S(t+1)/exp2/P-write runs
// under PV(t)'s MFMA cluster; V loads moved post-barrier (no vmcnt drain);
// branchless wrap so the loop body is one scheduling region.
// ---------------------------------------------------------------------------

typedef __bf16 bf16x8 __attribute__((ext_vector_type(8)));
typedef __bf16 bf16x2 __attribute__((ext_vector_type(2)));
typedef float f32x4 __attribute__((ext_vector_type(4)));
typedef unsigned int u32x4 __attribute__((ext_vector_type(4)));
typedef unsigned int u32;

#define L2E 1.4426950408889634f

__device__ __forceinline__ unsigned short f2bf(float f) {
    unsigned int u = __builtin_bit_cast(unsigned int, f);
    u += 0x7fffu + ((u >> 16) & 1u);   // RNE
    return (unsigned short)(u >> 16);
}
__device__ __forceinline__ u32 cvtpk(float a, float b) {
    bf16x2 t; t[0] = (__bf16)a; t[1] = (__bf16)b;   // -> v_cvt_pk_bf16_f32
    return __builtin_bit_cast(u32, t);
}
__device__ __forceinline__ bf16x8 ld8(const void* p) {
    u32x4 u = *reinterpret_cast<const u32x4*>(p);
    return __builtin_bit_cast(bf16x8, u);
}
__device__ __forceinline__ bf16x8 ldx(const float* p) {
    float4 a = *reinterpret_cast<const float4*>(p);
    float4 b = *reinterpret_cast<const float4*>(p + 4);
    u32x4 r;
    r.x = cvtpk(a.x, a.y); r.y = cvtpk(a.z, a.w);
    r.z = cvtpk(b.x, b.y); r.w = cvtpk(b.z, b.w);
    return __builtin_bit_cast(bf16x8, r);
}
__device__ __forceinline__ f32x4 mfma16(bf16x8 a, bf16x8 b, f32x4 c) {
    return __builtin_amdgcn_mfma_f32_16x16x32_bf16(a, b, c, 0, 0, 0);
}
__device__ __forceinline__ void gl2lds16(const void* g, void* l) {
    __builtin_amdgcn_global_load_lds(
        (const __attribute__((address_space(1))) u32*)g,
        (__attribute__((address_space(3))) u32*)l, 16, 0, 0);
}

// --------------------------- prep kernel -----------------------------------
// W -> staged layout [16 chunks q][4 slots s][640 cols c][8 bf16]:
//   (q,s,c,j) = W^T[c][k=32q+8s+j]; c<64: f (x log2e), c<128: g, else h.
__global__ __launch_bounds__(256) void cvt_w_all(const float* __restrict__ kf,
                                                 const float* __restrict__ kg,
                                                 const float* __restrict__ kh,
                                                 unsigned short* __restrict__ wst) {
    int idx = blockIdx.x * 256 + threadIdx.x;   // 327680 total
    int j = idx & 7;
    int gi = idx >> 3;
    int c = gi % 640;
    int sq = gi / 640;
    int k = (sq >> 2) * 32 + (sq & 3) * 8 + j;
    float v;
    if (c < 64)       v = kf[k * 64 + c] * L2E;
    else if (c < 128) v = kg[k * 64 + (c - 64)];
    else              v = kh[k * 512 + (c - 128)];
    wst[idx] = f2bf(v);
}

// --------------------- fused projection kernel -----------------------------
// Grid dim3(256, 2). W streamed via 2x20KB LDS dbuf (global_load_lds).
// Outputs:
//   fq  [16384][64]  : f rows (Q), row-major bf16
//   kst [4][64t][4jf][2ks][64l][16B] : K A-fragment stream
//   vst [4][64t][32c16][2ks][64l][16B] : V B-fragment stream (sigma j-order)
__global__ __launch_bounds__(256, 2) void proj_k(const float* __restrict__ x,
                                                 const unsigned short* __restrict__ wst,
                                                 unsigned short* __restrict__ fq,
                                                 unsigned short* __restrict__ kst,
                                                 unsigned short* __restrict__ vst) {
    __shared__ __align__(16) unsigned char Wl[2][20480];
    __shared__ unsigned short Tl[64][72];

    int m0 = blockIdx.x * 64;
    int grp = blockIdx.y;
    int tid = threadIdx.x;
    int w = tid >> 6, l = tid & 63, g = l >> 4, i = l & 15;

    const char* wsrc = (const char*)wst + (size_t)w * 10240 + (size_t)grp * 5120 + l * 16;

#pragma unroll
    for (int s5 = 0; s5 < 5; s5++)
        gl2lds16(wsrc + s5 * 1024, &Wl[0][w * 5120 + s5 * 1024]);

    const float* xrow = x + (size_t)(m0 + 16 * w + i) * 512 + g * 8;
    bf16x8 af[16];
#pragma unroll
    for (int k = 0; k < 16; k++) af[k] = ldx(xrow + 32 * k);

    f32x4 acc[5][4];
#pragma unroll
    for (int t = 0; t < 5; t++)
#pragma unroll
        for (int cf = 0; cf < 4; cf++) acc[t][cf] = f32x4{0, 0, 0, 0};

    int rdoff = g * 5120 + i * 16;

#pragma unroll
    for (int q = 0; q < 16; q++) {
        __syncthreads();
        if (q < 15) {
            const char* src = wsrc + (size_t)(q + 1) * 40960;
#pragma unroll
            for (int s5 = 0; s5 < 5; s5++)
                gl2lds16(src + s5 * 1024, &Wl[(q + 1) & 1][w * 5120 + s5 * 1024]);
        }
        const unsigned char* Wb = &Wl[q & 1][0];
        __builtin_amdgcn_s_setprio(1);
#pragma unroll
        for (int t = 0; t < 5; t++)
#pragma unroll
            for (int cf = 0; cf < 4; cf++) {
                bf16x8 bb = ld8(Wb + rdoff + (t * 64 + 16 * cf) * 16);
                acc[t][cf] = mfma16(af[q], bb, acc[t][cf]);
            }
        __builtin_amdgcn_s_setprio(0);
    }

    int batch = m0 >> 12;
    int kt = (m0 & 4095) >> 6;   // KV tile index (this block's 64 tokens)
    unsigned short* kbase = kst + (size_t)batch * 262144 + (size_t)kt * 4096;
    unsigned short* vbase = vst + (size_t)batch * 2097152 + (size_t)kt * 32768;

#pragma unroll
    for (int t = 0; t < 5; t++) {
        if (grp == 0 && t == 0) {
#pragma unroll
            for (int cf = 0; cf < 4; cf++)
#pragma unroll
                for (int r = 0; r < 4; r++)
                    fq[(size_t)(m0 + 16 * w + 4 * g + r) * 64 + 16 * cf + i] =
                        f2bf(acc[t][cf][r]);
        } else {
            __syncthreads();
#pragma unroll
            for (int cf = 0; cf < 4; cf++) {
                ushort4 v4;
                v4.x = f2bf(acc[t][cf][0]); v4.y = f2bf(acc[t][cf][1]);
                v4.z = f2bf(acc[t][cf][2]); v4.w = f2bf(acc[t][cf][3]);
                *reinterpret_cast<ushort4*>(&Tl[16 * cf + i][16 * w + 4 * g]) = v4;
            }
            __syncthreads();
            if (grp == 0 && t == 1) {
                // g tile -> K fragment stream
#pragma unroll
                for (int ch = tid; ch < 512; ch += 256) {
                    int jf2 = ch >> 7, ks = (ch >> 6) & 1, l2 = ch & 63;
                    int g2 = l2 >> 4, i2 = l2 & 15;
                    ushort4 o0, o1;
                    o0.x = Tl[ks * 32 + 8 * g2 + 0][16 * jf2 + i2];
                    o0.y = Tl[ks * 32 + 8 * g2 + 1][16 * jf2 + i2];
                    o0.z = Tl[ks * 32 + 8 * g2 + 2][16 * jf2 + i2];
                    o0.w = Tl[ks * 32 + 8 * g2 + 3][16 * jf2 + i2];
                    o1.x = Tl[ks * 32 + 8 * g2 + 4][16 * jf2 + i2];
                    o1.y = Tl[ks * 32 + 8 * g2 + 5][16 * jf2 + i2];
                    o1.z = Tl[ks * 32 + 8 * g2 + 6][16 * jf2 + i2];
                    o1.w = Tl[ks * 32 + 8 * g2 + 7][16 * jf2 + i2];
                    unsigned short* dst = kbase + (size_t)(jf2 * 1024 + ks * 512 + l2 * 8);
                    *reinterpret_cast<ushort4*>(dst)     = o0;
                    *reinterpret_cast<ushort4*>(dst + 4) = o1;
                }
            } else {
                // V tile -> B fragment stream (sigma j-order)
                int n0 = (grp == 0) ? (t - 2) * 64 : 192 + t * 64;
#pragma unroll
                for (int ch = tid; ch < 512; ch += 256) {
                    int cc = ch >> 7, ks = (ch >> 6) & 1, l2 = ch & 63;
                    int g2 = l2 >> 4, i2 = l2 & 15;
                    int row = cc * 16 + i2;
                    int jb = 32 * ks + 4 * g2;
                    ushort4 o0, o1;
                    o0.x = Tl[row][jb + 0];  o0.y = Tl[row][jb + 1];
                    o0.z = Tl[row][jb + 2];  o0.w = Tl[row][jb + 3];
                    o1.x = Tl[row][jb + 16]; o1.y = Tl[row][jb + 17];
                    o1.z = Tl[row][jb + 18]; o1.w = Tl[row][jb + 19];
                    int c16 = (n0 >> 4) + cc;
                    unsigned short* dst = vbase + (size_t)(c16 * 1024 + ks * 512 + l2 * 8);
                    *reinterpret_cast<ushort4*>(dst)     = o0;
                    *reinterpret_cast<ushort4*>(dst + 4) = o1;
                }
            }
        }
    }
}

// --------------------------- shared-P attention ----------------------------
// Grid 256 = 4 batch x 64 q-tiles(64 rows); block 512 thr / 8 waves.
// Software-pipelined: per iteration t (single barrier):
//   barrier -> V(t) loads -> P(t) read -> S(t+1) MFMA -> K(t+2) prefetch
//   -> PV(t) 32 MFMA (setprio) -> exp2/pack -> P(t+1) write.
// Branchless wrap (&63); lp masked at t=63. l via epilogue LDS atomic reduce.
__global__ __launch_bounds__(512, 2) void attn_k(const unsigned short* __restrict__ fq,
                                                 const unsigned short* __restrict__ kst,
                                                 const unsigned short* __restrict__ vst,
                                                 const float* __restrict__ x,
                                                 const float* __restrict__ gamma,
                                                 float* __restrict__ out) {
    __shared__ __align__(16) unsigned char Pl[2][8192];   // [buf][qf][ks][64l][16B]
    __shared__ float l_lds[64];

    int bid = blockIdx.x;
    int xcd = bid & 7;
    int batch = xcd >> 1;                       // 2 XCDs per batch
    int qidx = ((xcd & 1) << 5) | (bid >> 3);   // 0..63
    int q0 = qidx * 64;

    int tid = threadIdx.x;
    int w = tid >> 6, l = tid & 63, g = l >> 4, i = l & 15;
    int jf = w >> 1, qfh = w & 1;

    if (tid < 64) l_lds[tid] = 0.0f;

    const unsigned short* fqb = fq + (size_t)batch * 4096 * 64;
    const char* kb = (const char*)kst + (size_t)batch * 524288;
    const char* vb = (const char*)vst + (size_t)batch * 4194304;

    // Q fragments for this wave's two q-frags
    bf16x8 aQ[2][2];
#pragma unroll
    for (int qf_l = 0; qf_l < 2; qf_l++)
#pragma unroll
        for (int ks = 0; ks < 2; ks++)
            aQ[qf_l][ks] = ld8(fqb + (size_t)(q0 + 16 * (2 * qfh + qf_l) + i) * 64 +
                               ks * 32 + g * 8);

    f32x4 acc[4][4];
#pragma unroll
    for (int a = 0; a < 4; a++)
#pragma unroll
        for (int b = 0; b < 4; b++) acc[a][b] = f32x4{0, 0, 0, 0};
    float lp[2] = {0.0f, 0.0f};

    int pwoff = ((2 * qfh) * 2 + (jf >> 1)) * 1024 + l * 16 + (jf & 1) * 8;

    // ---- prologue: K(0) -> S(0) -> P(0) into buf0; then K(1) ----
    bf16x8 kA[2];
    kA[0] = ld8(kb + (size_t)jf * 2048 + l * 16);
    kA[1] = ld8(kb + (size_t)jf * 2048 + 1024 + l * 16);
    {
        f32x4 sacc[2] = {f32x4{0,0,0,0}, f32x4{0,0,0,0}};
#pragma unroll
        for (int qf_l = 0; qf_l < 2; qf_l++) {
            sacc[qf_l] = mfma16(kA[0], aQ[qf_l][0], sacc[qf_l]);
            sacc[qf_l] = mfma16(kA[1], aQ[qf_l][1], sacc[qf_l]);
        }
        kA[0] = ld8(kb + (size_t)(4 + jf) * 2048 + l * 16);
        kA[1] = ld8(kb + (size_t)(4 + jf) * 2048 + 1024 + l * 16);
#pragma unroll
        for (int qf_l = 0; qf_l < 2; qf_l++) {
            float p0 = __builtin_amdgcn_exp2f(sacc[qf_l][0]);
            float p1 = __builtin_amdgcn_exp2f(sacc[qf_l][1]);
            float p2 = __builtin_amdgcn_exp2f(sacc[qf_l][2]);
            float p3 = __builtin_amdgcn_exp2f(sacc[qf_l][3]);
            lp[qf_l] += (p0 + p1) + (p2 + p3);
            uint2 pk2;
            pk2.x = cvtpk(p0, p1);
            pk2.y = cvtpk(p2, p3);
            *reinterpret_cast<uint2*>(&Pl[0][0] + pwoff + qf_l * 2048) = pk2;
        }
    }

    for (int t = 0; t < 64; ++t) {
        __syncthreads();   // P(t) visible; buf (t+1)&1 free for writing

        // ---- V(t) loads (post-barrier: hidden under P-read + S-MFMA) ----
        bf16x8 vB[4][2];
#pragma unroll
        for (int cf = 0; cf < 4; cf++)
#pragma unroll
            for (int ks = 0; ks < 2; ks++)
                vB[cf][ks] = ld8(vb + (size_t)(t * 32 + w * 4 + cf) * 2048 +
                                 ks * 1024 + l * 16);

        // ---- P(t) read as A-fragments ----
        const unsigned char* Pr = &Pl[t & 1][0];
        bf16x8 aP[4][2];
#pragma unroll
        for (int qf = 0; qf < 4; qf++)
#pragma unroll
            for (int ks = 0; ks < 2; ks++)
                aP[qf][ks] = ld8(Pr + (qf * 2 + ks) * 1024 + l * 16);

        // ---- S(t+1) with kA = K(t+1) ----
        f32x4 sacc[2] = {f32x4{0,0,0,0}, f32x4{0,0,0,0}};
#pragma unroll
        for (int qf_l = 0; qf_l < 2; qf_l++) {
            sacc[qf_l] = mfma16(kA[0], aQ[qf_l][0], sacc[qf_l]);
            sacc[qf_l] = mfma16(kA[1], aQ[qf_l][1], sacc[qf_l]);
        }

        // ---- K(t+2) prefetch (wraps; in flight a full iteration) ----
        {
            int tk = (t + 2) & 63;
            const char* kn = kb + (size_t)(tk * 4 + jf) * 2048;
            kA[0] = ld8(kn + l * 16);
            kA[1] = ld8(kn + 1024 + l * 16);
        }

        // ---- PV(t): 32 MFMA (exp2/pack of t+1 interleaves on VALU) ----
        __builtin_amdgcn_s_setprio(1);
#pragma unroll
        for (int cf = 0; cf < 4; cf++)
#pragma unroll
            for (int qf = 0; qf < 4; qf++) {
                acc[qf][cf] = mfma16(aP[qf][0], vB[cf][0], acc[qf][cf]);
                acc[qf][cf] = mfma16(aP[qf][1], vB[cf][1], acc[qf][cf]);
            }
        __builtin_amdgcn_s_setprio(0);

        // ---- P(t+1) = exp2(S(t+1)), pack, write buf (t+1)&1 ----
        float msk = (t < 63) ? 1.0f : 0.0f;
        unsigned char* Pb = &Pl[(t + 1) & 1][0];
#pragma unroll
        for (int qf_l = 0; qf_l < 2; qf_l++) {
            float p0 = __builtin_amdgcn_exp2f(sacc[qf_l][0]);
            float p1 = __builtin_amdgcn_exp2f(sacc[qf_l][1]);
            float p2 = __builtin_amdgcn_exp2f(sacc[qf_l][2]);
            float p3 = __builtin_amdgcn_exp2f(sacc[qf_l][3]);
            lp[qf_l] += msk * ((p0 + p1) + (p2 + p3));
            uint2 pk2;
            pk2.x = cvtpk(p0, p1);
            pk2.y = cvtpk(p2, p3);
            *reinterpret_cast<uint2*>(Pb + pwoff + qf_l * 2048) = pk2;
        }
    }

    // ---- l reduction: in-wave over g, cross-wave (4 jf) via LDS atomics ----
#pragma unroll
    for (int qf_l = 0; qf_l < 2; qf_l++) {
        lp[qf_l] += __shfl_xor(lp[qf_l], 16, 64);
        lp[qf_l] += __shfl_xor(lp[qf_l], 32, 64);
    }
    if (g == 0) {
        atomicAdd(&l_lds[16 * (2 * qfh + 0) + i], lp[0]);
        atomicAdd(&l_lds[16 * (2 * qfh + 1) + i], lp[1]);
    }
    __syncthreads();

    // ---- epilogue: out = gamma*O/l + x ----
    float gam = gamma[0];
#pragma unroll
    for (int qf = 0; qf < 4; qf++) {
#pragma unroll
        for (int r = 0; r < 4; r++) {
            float linv = gam / l_lds[16 * qf + 4 * g + r];
            int n = q0 + 16 * qf + 4 * g + r;
            size_t base = ((size_t)batch * 4096 + n) * 512 + 64 * w;
#pragma unroll
            for (int cf = 0; cf < 4; cf++)
                out[base + 16 * cf + i] = acc[qf][cf][r] * linv + x[base + 16 * cf + i];
        }
    }
}

// --------------------------- launcher --------------------------------------

extern "C" void kernel_launch(void* const* d_in, const int* in_sizes, int n_in,
                              void* d_out, int out_size, void* d_ws, size_t ws_size,
                              hipStream_t stream) {
    const float* x = (const float*)d_in[0];
    const float* kf = (const float*)d_in[1];
    const float* kg = (const float*)d_in[2];
    const float* kh = (const float*)d_in[3];
    const float* gamma = (const float*)d_in[4];
    float* out = (float*)d_out;

    char* ws = (char*)d_ws;
    unsigned short* Fq  = (unsigned short*)(ws);               // 2 MB
    unsigned short* Kst = (unsigned short*)(ws + 2097152);     // 2 MB
    unsigned short* Vst = (unsigned short*)(ws + 4194304);     // 16 MB
    unsigned short* Wst = (unsigned short*)(ws + 20971520);    // 640 KB

    cvt_w_all<<<1280, 256, 0, stream>>>(kf, kg, kh, Wst);
    proj_k<<<dim3(256, 2), 256, 0, stream>>>(x, Wst, Fq, Kst, Vst);
    attn_k<<<256, 512, 0, stream>>>(Fq, Kst, Vst, x, gamma, out);
}